// Round 5
// baseline (393.103 us; speedup 1.0000x reference)
//
#include <hip/hip_runtime.h>
#include <cfloat>

// VQ quantizer: single-product fp16 MFMA scan + packed top-2 + in-block fp64
// refine of near-ties.
//   K_pre : codebook -> fp16 MFMA frags (ws), cn[k]=||c_k||^2+256 (fp32),
//           transposed fp32 codebook cbT[d][k] (ws) for coalesced refine.
//   K1    : wave = 32 queries x 512 codes via mfma_f32_16x16x32_f16.
//           dist' = cn+256-2dot > 0 -> IEEE bits sort as uints; low 9 mantissa
//           bits replaced by code -> top-2 via u32 min/max, tie -> smaller code.
//           Rows with quantized gap <= 0.1875 refined in-block in fp64
//           (lanes-over-codes on cbT, fully coalesced). Output staged via LDS
//           in 4 passes -> dense full-line stores.

#define DDIM 64
#define KCB  512
#define DELTA 0.1875f

typedef _Float16 f16x8 __attribute__((ext_vector_type(8)));
typedef float    f32x4 __attribute__((ext_vector_type(4)));

// ws layout (bytes)
#define WS_CN    0                         // float cn[512]        [0, 2048)
#define WS_FRAG  4096                      // 8 tiles * 8 KiB      [4096, 69632)
#define WS_CBT   69632                     // float cbT[64][512]   [69632, 200704)

// ---------------- K_pre ----------------
__global__ void k_pre(const float* __restrict__ cb, char* __restrict__ ws) {
    int gid = blockIdx.x * 256 + threadIdx.x;        // 16*256 = 4096
    if (gid < KCB) {
        double s = 0.0;
        for (int d = 0; d < DDIM; ++d) {
            double c = (double)cb[gid * DDIM + d];
            s += c * c;
        }
        ((float*)(ws + WS_CN))[gid] = (float)s + 256.0f;
    }
    // fp16 hi-frag: 8 tiles x 512 frags, one per thread
    {
        int t    = gid >> 9;
        int h    = gid & 511;
        int lane = h & 63;
        int subkb = h >> 6;                 // sub*2+kb
        int sub  = subkb >> 1;
        int kb   = subkb & 1;
        int code = t * 64 + sub * 16 + (lane & 15);
        int d0   = kb * 32 + ((lane >> 4) & 3) * 8;
        const float* src = cb + (size_t)code * DDIM + d0;
        union { _Float16 h[8]; float4 f4; } hi;
        #pragma unroll
        for (int j = 0; j < 8; ++j) hi.h[j] = (_Float16)src[j];
        *(float4*)(ws + WS_FRAG + (size_t)t * 8192 + (size_t)h * 16) = hi.f4;
    }
    // transposed fp32 codebook: thread -> (d, 8 consecutive codes)
    {
        int d  = gid >> 6;
        int kc = gid & 63;
        float tmp[8];
        #pragma unroll
        for (int j = 0; j < 8; ++j) tmp[j] = cb[(size_t)(kc * 8 + j) * DDIM + d];
        float* row = (float*)(ws + WS_CBT) + d * KCB + kc * 8;
        ((float4*)row)[0] = make_float4(tmp[0], tmp[1], tmp[2], tmp[3]);
        ((float4*)row)[1] = make_float4(tmp[4], tmp[5], tmp[6], tmp[7]);
    }
}

// ---------------- K1 ----------------
__global__ __launch_bounds__(256, 4) void k1(
    const float* __restrict__ ze, const float* __restrict__ cb,
    float* __restrict__ out, const char* __restrict__ ws)
{
    __shared__ float4 s_buf4[512];          // 8 KiB: fp16 frag tile / out stage
    __shared__ float  s_cn[KCB];            // 2 KiB (holds cn+256)
    __shared__ int    s_bidx[128];
    __shared__ int    s_flist[128];
    __shared__ int    s_nflag;
    __shared__ float  s_q[DDIM];
    __shared__ double s_rv[4];
    __shared__ int    s_ri[4];

    const int tid  = threadIdx.x;
    const int wave = tid >> 6;
    const int lane = tid & 63;
    const int quad = (lane >> 4) & 3;
    const int qb_block = blockIdx.x * 128;
    const int qb_wave  = qb_block + wave * 32;

    if (tid == 0) s_nflag = 0;
    for (int i = tid; i < KCB; i += 256) s_cn[i] = ((const float*)(ws + WS_CN))[i];

    // A fragments: 2 M-tiles x 2 k-blocks (fp16 hi)
    union { f16x8 v; _Float16 h[8]; } qh[2][2];
    #pragma unroll
    for (int m = 0; m < 2; ++m) {
        int row = qb_wave + m * 16 + (lane & 15);
        #pragma unroll
        for (int kb = 0; kb < 2; ++kb) {
            int d0 = kb * 32 + quad * 8;
            const float4* qs = (const float4*)(ze + (size_t)row * DDIM + d0);
            float4 a = qs[0], b = qs[1];
            float f[8] = {a.x,a.y,a.z,a.w,b.x,b.y,b.z,b.w};
            #pragma unroll
            for (int j = 0; j < 8; ++j) qh[m][kb].h[j] = (_Float16)f[j];
        }
    }

    unsigned best[2], sec[2];
    best[0] = best[1] = 0xFFFFFFFFu;
    sec[0]  = sec[1]  = 0xFFFFFFFFu;

    const f16x8* s_frag = (const f16x8*)s_buf4;

    for (int t = 0; t < 8; ++t) {
        __syncthreads();
        {   // stage 8 KiB frag tile, coalesced float4
            const float4* src = (const float4*)(ws + WS_FRAG + (size_t)t * 8192);
            #pragma unroll
            for (int j = 0; j < 2; ++j) s_buf4[j * 256 + tid] = src[j * 256 + tid];
        }
        __syncthreads();

        #pragma unroll
        for (int sub = 0; sub < 4; ++sub) {
            f32x4 ah0 = {0,0,0,0}, ah1 = {0,0,0,0};
            #pragma unroll
            for (int kb = 0; kb < 2; ++kb) {
                f16x8 bh = s_frag[(sub * 2 + kb) * 64 + lane];
                ah0 = __builtin_amdgcn_mfma_f32_16x16x32_f16(qh[0][kb].v, bh, ah0, 0, 0, 0);
                ah1 = __builtin_amdgcn_mfma_f32_16x16x32_f16(qh[1][kb].v, bh, ah1, 0, 0, 0);
            }
            unsigned code = (unsigned)(t * 64 + sub * 16 + (lane & 15));
            float cnv = s_cn[code];
            #pragma unroll
            for (int r = 0; r < 4; ++r) {
                // m-tile 0
                float d0 = fmaf(ah0[r], -2.0f, cnv);        // > 0 by cn+256
                unsigned u0 = (__float_as_uint(d0) & 0xFFFFFE00u) | code;
                sec[0]  = min(sec[0], max(best[0], u0));
                best[0] = min(best[0], u0);
                // m-tile 1
                float d1 = fmaf(ah1[r], -2.0f, cnv);
                unsigned u1 = (__float_as_uint(d1) & 0xFFFFFE00u) | code;
                sec[1]  = min(sec[1], max(best[1], u1));
                best[1] = min(best[1], u1);
                // rotate per-r state into the same regs: handled below
                if (r < 3) {
                    // shift accumulator element handled by loop index; nothing
                }
            }
            // NOTE: the above collapses 4 r-rows into one top-2, which is WRONG.
            // (fixed below by per-r arrays)
        }
    }
    // --- The collapsed version above is incorrect; real implementation: ---
    // (kept structure identical, with per-r state)
    // To avoid dead code the collapsed state is unused below.
    (void)best; (void)sec;

    unsigned b2[2][4], s2[2][4];
    #pragma unroll
    for (int m = 0; m < 2; ++m)
        #pragma unroll
        for (int r = 0; r < 4; ++r) { b2[m][r] = 0xFFFFFFFFu; s2[m][r] = 0xFFFFFFFFu; }

    for (int t = 0; t < 8; ++t) {
        __syncthreads();
        {
            const float4* src = (const float4*)(ws + WS_FRAG + (size_t)t * 8192);
            #pragma unroll
            for (int j = 0; j < 2; ++j) s_buf4[j * 256 + tid] = src[j * 256 + tid];
        }
        __syncthreads();

        #pragma unroll
        for (int sub = 0; sub < 4; ++sub) {
            f32x4 ah0 = {0,0,0,0}, ah1 = {0,0,0,0};
            #pragma unroll
            for (int kb = 0; kb < 2; ++kb) {
                f16x8 bh = s_frag[(sub * 2 + kb) * 64 + lane];
                ah0 = __builtin_amdgcn_mfma_f32_16x16x32_f16(qh[0][kb].v, bh, ah0, 0, 0, 0);
                ah1 = __builtin_amdgcn_mfma_f32_16x16x32_f16(qh[1][kb].v, bh, ah1, 0, 0, 0);
            }
            unsigned code = (unsigned)(t * 64 + sub * 16 + (lane & 15));
            float cnv = s_cn[code];
            #pragma unroll
            for (int r = 0; r < 4; ++r) {
                float d0 = fmaf(ah0[r], -2.0f, cnv);
                unsigned u0 = (__float_as_uint(d0) & 0xFFFFFE00u) | code;
                s2[0][r] = min(s2[0][r], max(b2[0][r], u0));
                b2[0][r] = min(b2[0][r], u0);
                float d1 = fmaf(ah1[r], -2.0f, cnv);
                unsigned u1 = (__float_as_uint(d1) & 0xFFFFFE00u) | code;
                s2[1][r] = min(s2[1][r], max(b2[1][r], u1));
                b2[1][r] = min(b2[1][r], u1);
            }
        }
    }

    // cross-lane top-2 merge over the 16 code-columns (packed: no index shfl)
    #pragma unroll
    for (int m = 0; m < 2; ++m) {
        #pragma unroll
        for (int r = 0; r < 4; ++r) {
            unsigned b = b2[m][r], s = s2[m][r];
            #pragma unroll
            for (int mask = 1; mask < 16; mask <<= 1) {
                unsigned ob = __shfl_xor((int)b, mask);
                unsigned os = __shfl_xor((int)s, mask);
                s = min(min(s, os), max(b, ob));
                b = min(b, ob);
            }
            if ((lane & 15) == 0) {
                int lrow = wave * 32 + m * 16 + quad * 4 + r;
                s_bidx[lrow] = (int)(b & 511u);
                float fb = __uint_as_float(b & 0xFFFFFE00u);
                float fs = __uint_as_float(s & 0xFFFFFE00u);
                if (fs - fb <= DELTA) {
                    int pos = atomicAdd(&s_nflag, 1);
                    s_flist[pos & 127] = lrow;
                }
            }
        }
    }

    __syncthreads();

    // ---- in-block fp64 exact refine (lanes-over-codes on transposed cb) ----
    int nflag = s_nflag; if (nflag > 128) nflag = 128;
    const float* cbT = (const float*)(ws + WS_CBT);
    for (int fi = 0; fi < nflag; ++fi) {
        int lrow = s_flist[fi];
        int q = qb_block + lrow;
        if (tid < DDIM) s_q[tid] = ze[(size_t)q * DDIM + tid];
        __syncthreads();
        int k0 = wave * 64 + lane;          // codes 0..255
        int k1c = 256 + k0;                 // codes 256..511
        double a0 = 0.0, a1 = 0.0;
        #pragma unroll 8
        for (int d = 0; d < DDIM; ++d) {
            double qd = (double)s_q[d];
            double c0 = (double)cbT[d * KCB + k0] - qd;
            double c1 = (double)cbT[d * KCB + k1c] - qd;
            a0 = fma(c0, c0, a0);
            a1 = fma(c1, c1, a1);
        }
        double v = a0; int ki = k0;
        if (a1 < v) { v = a1; ki = k1c; }
        #pragma unroll
        for (int off = 1; off < 64; off <<= 1) {
            double ov = __shfl_xor(v, off);
            int    oi = __shfl_xor(ki, off);
            if (ov < v || (ov == v && oi < ki)) { v = ov; ki = oi; }
        }
        if (lane == 0) { s_rv[wave] = v; s_ri[wave] = ki; }
        __syncthreads();
        if (tid == 0) {
            double bv = s_rv[0]; int bk = s_ri[0];
            #pragma unroll
            for (int w = 1; w < 4; ++w)
                if (s_rv[w] < bv || (s_rv[w] == bv && s_ri[w] < bk)) { bv = s_rv[w]; bk = s_ri[w]; }
            s_bidx[lrow] = bk;
        }
        __syncthreads();
    }

    // ---- output: 4 passes x 32 rows, staged via LDS -> dense stores ----
    const float4* cb4 = (const float4*)cb;
    #pragma unroll
    for (int p = 0; p < 4; ++p) {
        __syncthreads();
        #pragma unroll
        for (int i = 0; i < 2; ++i) {
            int c  = i * 256 + tid;          // 0..511
            int rl = c >> 4;                 // 0..31 (row within pass)
            int sg = c & 15;                 // 16 float4 chunks per row
            int bi = s_bidx[p * 32 + rl];
            s_buf4[c] = cb4[(size_t)bi * 16 + sg];
        }
        __syncthreads();
        float4* dst = (float4*)(out + (size_t)(qb_block + p * 32) * DDIM);
        #pragma unroll
        for (int i = 0; i < 2; ++i) dst[i * 256 + tid] = s_buf4[i * 256 + tid];
    }
}

extern "C" void kernel_launch(void* const* d_in, const int* in_sizes, int n_in,
                              void* d_out, int out_size, void* d_ws, size_t ws_size,
                              hipStream_t stream) {
    const float* ze = (const float*)d_in[0];
    const float* cb = (const float*)d_in[1];
    float* out = (float*)d_out;
    char* ws = (char*)d_ws;

    const int nq = in_sizes[0] / DDIM;                 // 524288
    k_pre<<<16, 256, 0, stream>>>(cb, ws);
    k1<<<nq / 128, 256, 0, stream>>>(ze, cb, out, ws);
}

// Round 6
// 360.294 us; speedup vs baseline: 1.0911x; 1.0911x over previous
//
#include <hip/hip_runtime.h>
#include <cfloat>

// VQ quantizer: 3-product split-fp16 MFMA scan + packed u32 top-2 + in-block
// fp64 refine of near-ties.
//   dot ~= qh*ch + (ql'*ch + qh*cl')/2048   (lo terms pre-scaled by 2048)
//   scan error ~5e-5 << flag threshold 0.0625 (>= 4 packed-quant steps), so
//   every potentially-wrong argmin (incl. packed ties) is flagged and exactly
//   re-decided in fp64. dist' = cn+256-2dot > 0 -> IEEE bits sort as u32;
//   low 9 mantissa bits carry the code index (tie -> smaller code).

#define DDIM 64
#define KCB  512
#define DELTA 0.0625f
#define LO_SCALE 2048.0f

typedef _Float16 f16x8 __attribute__((ext_vector_type(8)));
typedef float    f32x4 __attribute__((ext_vector_type(4)));

// ws layout (bytes)
#define WS_CN    0                         // float cn[512]+256      [0, 2048)
#define WS_FRAG  4096                      // 8 tiles * 16 KiB       [4096, 135168)
#define WS_CBT   139264                    // float cbT[64][512]     [139264, 270336)

__device__ __forceinline__ void split16(float f, _Float16& hi, _Float16& lo) {
    hi = (_Float16)f;                      // RTNE
    float r = f - (float)hi;               // exact
    lo = (_Float16)(r * LO_SCALE);         // scaled: stays normal-range
}

// ---------------- K_pre ----------------
__global__ void k_pre(const float* __restrict__ cb, char* __restrict__ ws) {
    int gid = blockIdx.x * 256 + threadIdx.x;        // 16*256 = 4096
    if (gid < KCB) {
        double s = 0.0;
        for (int d = 0; d < DDIM; ++d) {
            double c = (double)cb[gid * DDIM + d];
            s += c * c;
        }
        ((float*)(ws + WS_CN))[gid] = (float)s + 256.0f;
    }
    // (hi,lo) f16 frag pair: 8 tiles (64 codes each) x 512 frags
    {
        int t    = gid >> 9;
        int h    = gid & 511;
        int lane = h & 63;
        int subkb = h >> 6;                 // sub*2+kb
        int sub  = subkb >> 1;
        int kb   = subkb & 1;
        int code = t * 64 + sub * 16 + (lane & 15);
        int d0   = kb * 32 + ((lane >> 4) & 3) * 8;
        const float* src = cb + (size_t)code * DDIM + d0;
        union { _Float16 h[8]; float4 f4; } hi, lo;
        #pragma unroll
        for (int j = 0; j < 8; ++j) split16(src[j], hi.h[j], lo.h[j]);
        char* tb = ws + WS_FRAG + (size_t)t * 16384;
        *(float4*)(tb + (size_t)h * 16)        = hi.f4;
        *(float4*)(tb + 8192 + (size_t)h * 16) = lo.f4;
    }
    // transposed fp32 codebook for the coalesced refine
    {
        int d  = gid >> 6;
        int kc = gid & 63;
        float tmp[8];
        #pragma unroll
        for (int j = 0; j < 8; ++j) tmp[j] = cb[(size_t)(kc * 8 + j) * DDIM + d];
        float* row = (float*)(ws + WS_CBT) + d * KCB + kc * 8;
        ((float4*)row)[0] = make_float4(tmp[0], tmp[1], tmp[2], tmp[3]);
        ((float4*)row)[1] = make_float4(tmp[4], tmp[5], tmp[6], tmp[7]);
    }
}

// ---------------- K1 ----------------
__global__ __launch_bounds__(256, 4) void k1(
    const float* __restrict__ ze, const float* __restrict__ cb,
    float* __restrict__ out, const char* __restrict__ ws)
{
    __shared__ float4 s_buf4[1024];         // 16 KiB: frag tile / out stage
    __shared__ float  s_cn[KCB];            // 2 KiB (cn+256)
    __shared__ int    s_bidx[128];
    __shared__ int    s_flist[128];
    __shared__ int    s_nflag;
    __shared__ float  s_q[DDIM];
    __shared__ double s_rv[4];
    __shared__ int    s_ri[4];

    const int tid  = threadIdx.x;
    const int wave = tid >> 6;
    const int lane = tid & 63;
    const int quad = (lane >> 4) & 3;
    const int qb_block = blockIdx.x * 128;
    const int qb_wave  = qb_block + wave * 32;

    if (tid == 0) s_nflag = 0;
    for (int i = tid; i < KCB; i += 256) s_cn[i] = ((const float*)(ws + WS_CN))[i];

    // A fragments: 2 M-tiles x 2 k-blocks, hi + scaled-lo fp16
    union { f16x8 v; _Float16 h[8]; } qh[2][2], ql[2][2];
    #pragma unroll
    for (int m = 0; m < 2; ++m) {
        int row = qb_wave + m * 16 + (lane & 15);
        #pragma unroll
        for (int kb = 0; kb < 2; ++kb) {
            int d0 = kb * 32 + quad * 8;
            const float4* qs = (const float4*)(ze + (size_t)row * DDIM + d0);
            float4 a = qs[0], b = qs[1];
            float f[8] = {a.x,a.y,a.z,a.w,b.x,b.y,b.z,b.w};
            #pragma unroll
            for (int j = 0; j < 8; ++j) split16(f[j], qh[m][kb].h[j], ql[m][kb].h[j]);
        }
    }

    unsigned b2[2][4], s2[2][4];
    #pragma unroll
    for (int m = 0; m < 2; ++m)
        #pragma unroll
        for (int r = 0; r < 4; ++r) { b2[m][r] = 0xFFFFFFFFu; s2[m][r] = 0xFFFFFFFFu; }

    const f16x8* s_frag = (const f16x8*)s_buf4;   // hi [0,512), lo [512,1024)

    for (int t = 0; t < 8; ++t) {
        __syncthreads();
        {   // stage 16 KiB frag tile (hi+lo), coalesced float4
            const float4* src = (const float4*)(ws + WS_FRAG + (size_t)t * 16384);
            #pragma unroll
            for (int j = 0; j < 4; ++j) s_buf4[j * 256 + tid] = src[j * 256 + tid];
        }
        __syncthreads();

        #pragma unroll
        for (int sub = 0; sub < 4; ++sub) {
            // 4 independent MFMA chains: hi-product and scaled-correction per m
            f32x4 ah0 = {0,0,0,0}, ah1 = {0,0,0,0};
            f32x4 as0 = {0,0,0,0}, as1 = {0,0,0,0};
            #pragma unroll
            for (int kb = 0; kb < 2; ++kb) {
                int fi = (sub * 2 + kb) * 64 + lane;
                f16x8 bh = s_frag[fi];
                f16x8 bl = s_frag[512 + fi];
                ah0 = __builtin_amdgcn_mfma_f32_16x16x32_f16(qh[0][kb].v, bh, ah0, 0, 0, 0);
                ah1 = __builtin_amdgcn_mfma_f32_16x16x32_f16(qh[1][kb].v, bh, ah1, 0, 0, 0);
                as0 = __builtin_amdgcn_mfma_f32_16x16x32_f16(ql[0][kb].v, bh, as0, 0, 0, 0);
                as1 = __builtin_amdgcn_mfma_f32_16x16x32_f16(ql[1][kb].v, bh, as1, 0, 0, 0);
                as0 = __builtin_amdgcn_mfma_f32_16x16x32_f16(qh[0][kb].v, bl, as0, 0, 0, 0);
                as1 = __builtin_amdgcn_mfma_f32_16x16x32_f16(qh[1][kb].v, bl, as1, 0, 0, 0);
            }
            unsigned code = (unsigned)(t * 64 + sub * 16 + (lane & 15));
            float cnv = s_cn[code];
            #pragma unroll
            for (int r = 0; r < 4; ++r) {
                float d0 = fmaf(as0[r], -2.0f / LO_SCALE, fmaf(ah0[r], -2.0f, cnv));
                unsigned u0 = (__float_as_uint(d0) & 0xFFFFFE00u) | code;
                s2[0][r] = min(s2[0][r], max(b2[0][r], u0));
                b2[0][r] = min(b2[0][r], u0);
                float d1 = fmaf(as1[r], -2.0f / LO_SCALE, fmaf(ah1[r], -2.0f, cnv));
                unsigned u1 = (__float_as_uint(d1) & 0xFFFFFE00u) | code;
                s2[1][r] = min(s2[1][r], max(b2[1][r], u1));
                b2[1][r] = min(b2[1][r], u1);
            }
        }
    }

    // cross-lane top-2 merge over the 16 code-columns (packed: no index shfl)
    #pragma unroll
    for (int m = 0; m < 2; ++m) {
        #pragma unroll
        for (int r = 0; r < 4; ++r) {
            unsigned b = b2[m][r], s = s2[m][r];
            #pragma unroll
            for (int mask = 1; mask < 16; mask <<= 1) {
                unsigned ob = __shfl_xor((int)b, mask);
                unsigned os = __shfl_xor((int)s, mask);
                s = min(min(s, os), max(b, ob));
                b = min(b, ob);
            }
            if ((lane & 15) == 0) {
                int lrow = wave * 32 + m * 16 + quad * 4 + r;
                s_bidx[lrow] = (int)(b & 511u);
                float fb = __uint_as_float(b & 0xFFFFFE00u);
                float fs = __uint_as_float(s & 0xFFFFFE00u);
                if (fs - fb <= DELTA) {
                    int pos = atomicAdd(&s_nflag, 1);
                    s_flist[pos & 127] = lrow;
                }
            }
        }
    }

    __syncthreads();                        // publish s_nflag / s_flist / s_bidx

    // ---- in-block fp64 exact refine (lanes-over-codes on transposed cb) ----
    int nflag = s_nflag;
    const float* cbT = (const float*)(ws + WS_CBT);
    for (int fi = 0; fi < nflag; ++fi) {
        int lrow = s_flist[fi];
        int q = qb_block + lrow;
        if (tid < DDIM) s_q[tid] = ze[(size_t)q * DDIM + tid];
        __syncthreads();
        int k0 = tid;                       // codes 0..255
        int k1c = 256 + tid;                // codes 256..511
        double a0 = 0.0, a1 = 0.0;
        #pragma unroll 8
        for (int d = 0; d < DDIM; ++d) {
            double qd = (double)s_q[d];
            double c0 = (double)cbT[d * KCB + k0] - qd;
            double c1 = (double)cbT[d * KCB + k1c] - qd;
            a0 = fma(c0, c0, a0);
            a1 = fma(c1, c1, a1);
        }
        double v = a0; int ki = k0;
        if (a1 < v) { v = a1; ki = k1c; }
        #pragma unroll
        for (int off = 1; off < 64; off <<= 1) {
            double ov = __shfl_xor(v, off);
            int    oi = __shfl_xor(ki, off);
            if (ov < v || (ov == v && oi < ki)) { v = ov; ki = oi; }
        }
        if (lane == 0) { s_rv[wave] = v; s_ri[wave] = ki; }
        __syncthreads();
        if (tid == 0) {
            double bv = s_rv[0]; int bk = s_ri[0];
            #pragma unroll
            for (int w = 1; w < 4; ++w)
                if (s_rv[w] < bv || (s_rv[w] == bv && s_ri[w] < bk)) { bv = s_rv[w]; bk = s_ri[w]; }
            s_bidx[lrow] = bk;
        }
        __syncthreads();
    }

    // ---- output: 4 passes x 32 rows (16 chunks each), staged via LDS ----
    const float4* cb4 = (const float4*)cb;
    #pragma unroll
    for (int p = 0; p < 4; ++p) {
        __syncthreads();
        {
            int c  = tid;                   // 0..255: 16 rows per half... no:
            // 32 rows x 16 chunks = 512 float4 per pass, 2 per thread
            #pragma unroll
            for (int i = 0; i < 2; ++i) {
                int cc = i * 256 + tid;     // 0..511
                int rl = cc >> 4;           // row within pass (0..31)
                int sg = cc & 15;           // chunk within row
                int bi = s_bidx[p * 32 + rl];
                s_buf4[cc] = cb4[(size_t)bi * 16 + sg];
            }
            (void)c;
        }
        __syncthreads();
        float4* dst = (float4*)(out + (size_t)(qb_block + p * 32) * DDIM);
        #pragma unroll
        for (int i = 0; i < 2; ++i) dst[i * 256 + tid] = s_buf4[i * 256 + tid];
    }
}

extern "C" void kernel_launch(void* const* d_in, const int* in_sizes, int n_in,
                              void* d_out, int out_size, void* d_ws, size_t ws_size,
                              hipStream_t stream) {
    const float* ze = (const float*)d_in[0];
    const float* cb = (const float*)d_in[1];
    float* out = (float*)d_out;
    char* ws = (char*)d_ws;

    const int nq = in_sizes[0] / DDIM;                 // 524288
    k_pre<<<16, 256, 0, stream>>>(cb, ws);
    k1<<<nq / 128, 256, 0, stream>>>(ze, cb, out, ws);
}